// Round 14
// baseline (337.090 us; speedup 1.0000x reference)
//
#include <hip/hip_runtime.h>
#include <hip/hip_fp16.h>

#define NNODES 50000
#define NEDGES 800000
#define IN_FEAT 128
#define OUT_FEAT 64
#define NH 4
#define HD 16

#define XS_P 132   // xs pitch (floats): %4==0 for b128, %32==4 -> conflict-free
#define WS_P 196   // ws pitch (floats): %4==0 for b128, %32==4 -> conflict-free
#define CAP 96     // per-dst bucket capacity; deg ~ Poisson(16), P(>96) ~ 1e-10

// ---------------------------------------------------------------------------
// Detect whether edge_index arrived as int64 (reference dtype) or int32.
// ---------------------------------------------------------------------------
__global__ void detect_kernel(const void* __restrict__ ei, int* __restrict__ flag) {
    const unsigned long long* p = (const unsigned long long*)ei;
    unsigned long long v = p[threadIdx.x];
    if (v >> 32) atomicOr(flag, 1);
}

__device__ __forceinline__ float r16(float x) {
    x += __shfl_xor(x, 1, 16);
    x += __shfl_xor(x, 2, 16);
    x += __shfl_xor(x, 4, 16);
    x += __shfl_xor(x, 8, 16);
    return x;
}

// reduce over the 4 lanes sharing tx>>2 (one head's 16 dims = 4 threads x 4)
__device__ __forceinline__ float r4(float x) {
    x += __shfl_xor(x, 1, 4);
    x += __shfl_xor(x, 2, 4);
    return x;
}

// ---------------------------------------------------------------------------
// Fused QKV GEMM + PER-HEAD Minkowski normalize + fp16 pack. (unchanged r9/r10)
// qv2[n*64+d] = half2{qn[d], v[d]}; ktn[n*64+d] = fp32 kn (sign folded).
// ---------------------------------------------------------------------------
__global__ __launch_bounds__(256) void qkv_kernel(
        const float* __restrict__ x,
        const float* __restrict__ Wq, const float* __restrict__ bq,
        const float* __restrict__ Wk, const float* __restrict__ bk,
        const float* __restrict__ Wv, const float* __restrict__ bv,
        __half2* __restrict__ qv2, float* __restrict__ ktn) {
    __shared__ float xs[64 * XS_P];    // 33.8 KB
    __shared__ float ws[16 * WS_P];    // 12.5 KB
    const int tid = threadIdx.x;
    const int nb = blockIdx.x * 64;
    const int tx = tid & 15;           // dim group: d = tx*4 + j
    const int ty = tid >> 4;           // node group: n = nb + ty + 16*ii

#pragma unroll
    for (int j = 0; j < 8; ++j) {
        int f4 = tid + j * 256;        // 0..2047
        int r = f4 >> 5, c = (f4 & 31) * 4;
        int n = nb + r; if (n >= NNODES) n = NNODES - 1;
        float4 vx = *(const float4*)(x + (size_t)n * IN_FEAT + c);
        *(float4*)(xs + r * XS_P + c) = vx;
    }

    float acc[4][12];                  // [node ii][g*4+j], g=0:q 1:k 2:v
#pragma unroll
    for (int ii = 0; ii < 4; ++ii)
#pragma unroll
        for (int jj = 0; jj < 12; ++jj) acc[ii][jj] = 0.0f;

    for (int ch = 0; ch < 8; ++ch) {
        __syncthreads();
#pragma unroll
        for (int jj = 0; jj < 12; ++jj) {
            int i = tid + jj * 256;    // 0..3071
            int r = i >> 4, kk = i & 15;
            const float* W = (r < 64) ? Wq : (r < 128) ? Wk : Wv;
            ws[kk * WS_P + r] = W[(r & 63) * IN_FEAT + ch * 16 + kk];
        }
        __syncthreads();
#pragma unroll
        for (int kk = 0; kk < 16; ++kk) {
            int k = ch * 16 + kk;
            float4 wq4 = *(const float4*)(ws + kk * WS_P + tx * 4);
            float4 wk4 = *(const float4*)(ws + kk * WS_P + 64 + tx * 4);
            float4 wv4 = *(const float4*)(ws + kk * WS_P + 128 + tx * 4);
            float xv[4];
#pragma unroll
            for (int ii = 0; ii < 4; ++ii) xv[ii] = xs[(ty + 16 * ii) * XS_P + k];
#pragma unroll
            for (int ii = 0; ii < 4; ++ii) {
                acc[ii][0] = fmaf(xv[ii], wq4.x, acc[ii][0]);
                acc[ii][1] = fmaf(xv[ii], wq4.y, acc[ii][1]);
                acc[ii][2] = fmaf(xv[ii], wq4.z, acc[ii][2]);
                acc[ii][3] = fmaf(xv[ii], wq4.w, acc[ii][3]);
                acc[ii][4] = fmaf(xv[ii], wk4.x, acc[ii][4]);
                acc[ii][5] = fmaf(xv[ii], wk4.y, acc[ii][5]);
                acc[ii][6] = fmaf(xv[ii], wk4.z, acc[ii][6]);
                acc[ii][7] = fmaf(xv[ii], wk4.w, acc[ii][7]);
                acc[ii][8]  = fmaf(xv[ii], wv4.x, acc[ii][8]);
                acc[ii][9]  = fmaf(xv[ii], wv4.y, acc[ii][9]);
                acc[ii][10] = fmaf(xv[ii], wv4.z, acc[ii][10]);
                acc[ii][11] = fmaf(xv[ii], wv4.w, acc[ii][11]);
            }
        }
    }

    float bqr[4], bkr[4], bvr[4];
#pragma unroll
    for (int j = 0; j < 4; ++j) {
        bqr[j] = bq[tx * 4 + j];
        bkr[j] = bk[tx * 4 + j];
        bvr[j] = bv[tx * 4 + j];
    }
    const float slast = ((tx & 3) == 3) ? -1.0f : 1.0f;

#pragma unroll
    for (int ii = 0; ii < 4; ++ii) {
        int n = nb + ty + 16 * ii;
        float qr[4], kr[4], vr[4];
#pragma unroll
        for (int j = 0; j < 4; ++j) {
            qr[j] = acc[ii][j] + bqr[j];
            kr[j] = acc[ii][4 + j] + bkr[j];
            vr[j] = acc[ii][8 + j] + bvr[j];
        }
        float lq = qr[0]*qr[0] + qr[1]*qr[1] + qr[2]*qr[2] + slast * qr[3]*qr[3];
        float lk = kr[0]*kr[0] + kr[1]*kr[1] + kr[2]*kr[2] + slast * kr[3]*kr[3];
        float aa = r4(lq);             // per-head <q,q>_M
        float bb = r4(lk);             // per-head <k,k>_M
        float rsa = __builtin_amdgcn_rsqf(fmaxf(fabsf(aa), 1e-12f));
        float rsb = __builtin_amdgcn_rsqf(fmaxf(fabsf(bb), 1e-12f));
        float kn[4];
        __half2 h[4];
#pragma unroll
        for (int j = 0; j < 4; ++j) {
            h[j] = __floats2half2_rn(qr[j] * rsa, vr[j]);
            kn[j] = kr[j] * rsb;
        }
        kn[3] *= slast;                // fold Minkowski sign into stored kn
        if (n < NNODES) {
            *(float4*)(qv2 + (size_t)n * 64 + tx * 4) = *(float4*)h;
            *(float4*)(ktn + (size_t)n * 64 + tx * 4) = make_float4(kn[0], kn[1], kn[2], kn[3]);
        }
    }
}

// ---------------------------------------------------------------------------
// One-pass bucketed CSR build (unchanged r10).
// ---------------------------------------------------------------------------
__global__ void build_kernel(const void* __restrict__ ei, const int* __restrict__ mode,
                             int* __restrict__ deg, int* __restrict__ ssrc) {
    int e = blockIdx.x * blockDim.x + threadIdx.x;
    if (e >= NEDGES) return;
    int si, di;
    if (*mode) {
        const int* p = (const int*)ei;
        si = p[e]; di = p[NEDGES + e];
    } else {
        const long long* p = (const long long*)ei;
        si = (int)p[e]; di = (int)p[NEDGES + e];
    }
    int pos = atomicAdd(&deg[di], 1);
    if (pos < CAP) ssrc[di * CAP + pos] = si;
}

// ---------------------------------------------------------------------------
// Fused gather-aggregate, LANE-PER-(EDGE,HEAD): wave per dst node, lane =
// h*16 + es. Lane es of head h processes edges es, es+16, ... : loads the
// (src, h) 64B slice of qv2 (16 interleaved half2{qn,v}), computes the
// 16-dim dot against register-resident kt[16] (fp32, hoisted), accumulates a
// private 16-dim acc. NO shuffles in the hot loop. Epilogue: 4-round
// butterfly transpose-reduce puts dim-es totals on lane es (static reg
// indices, cndmask selects), then r16 for ss/den and the Wo GEMM (unchanged).
// ---------------------------------------------------------------------------
__global__ __launch_bounds__(256) void agg_kernel(
        const int* __restrict__ deg, const int* __restrict__ ssrc,
        const __half2* __restrict__ qv2, const float* __restrict__ ktn,
        const float* __restrict__ Wo, const float* __restrict__ bo,
        float* __restrict__ out) {
    __shared__ float atts[256];
    const int tid = threadIdx.x;
    const int n = blockIdx.x * 4 + (tid >> 6);
    const int t = tid & 63;
    const int h = t >> 4;              // head
    const int es = t & 15;             // edge slot

    // hoist this head's normalized kt into registers (fp32, 64B)
    float kf[16];
    {
        const float4* kp = (const float4*)(ktn + n * 64 + h * 16);
        float4 k0 = kp[0], k1 = kp[1], k2 = kp[2], k3 = kp[3];
        kf[0]=k0.x; kf[1]=k0.y; kf[2]=k0.z; kf[3]=k0.w;
        kf[4]=k1.x; kf[5]=k1.y; kf[6]=k1.z; kf[7]=k1.w;
        kf[8]=k2.x; kf[9]=k2.y; kf[10]=k2.z; kf[11]=k2.w;
        kf[12]=k3.x; kf[13]=k3.y; kf[14]=k3.z; kf[15]=k3.w;
    }

    int cnt = deg[n]; if (cnt > CAP) cnt = CAP;
    const int base0 = n * CAP;
    const float4* qp = (const float4*)qv2;   // 4 dwords = 4 interleaved dims

    float acc[16];
#pragma unroll
    for (int d = 0; d < 16; ++d) acc[d] = 0.0f;
    float den = 0.0f;

    for (int base = 0; base < cnt; base += 16) {
        int idx = base + es;
        bool on = idx < cnt;
        int sv = on ? ssrc[base0 + idx] : 0;
        int q4 = sv * 16 + h * 4;
        float4 A = qp[q4], B = qp[q4 + 1], C = qp[q4 + 2], D = qp[q4 + 3];
        float qd[16], vd[16];
        {
            const __half2* pa = (const __half2*)&A;
            const __half2* pb = (const __half2*)&B;
            const __half2* pc = (const __half2*)&C;
            const __half2* pd = (const __half2*)&D;
#pragma unroll
            for (int j = 0; j < 4; ++j) {
                float2 fa = __half22float2(pa[j]); qd[j]      = fa.x; vd[j]      = fa.y;
                float2 fb = __half22float2(pb[j]); qd[4 + j]  = fb.x; vd[4 + j]  = fb.y;
                float2 fc = __half22float2(pc[j]); qd[8 + j]  = fc.x; vd[8 + j]  = fc.y;
                float2 fd = __half22float2(pd[j]); qd[12 + j] = fd.x; vd[12 + j] = fd.y;
            }
        }
        // 16-dim dot, 4 independent partial chains for ILP
        float d0 = 0.0f, d1 = 0.0f, d2 = 0.0f, d3 = 0.0f;
#pragma unroll
        for (int j = 0; j < 4; ++j) {
            d0 = fmaf(qd[j],      kf[j],      d0);
            d1 = fmaf(qd[4 + j],  kf[4 + j],  d1);
            d2 = fmaf(qd[8 + j],  kf[8 + j],  d2);
            d3 = fmaf(qd[12 + j], kf[12 + j], d3);
        }
        float dot = (d0 + d1) + (d2 + d3);
        float xv = fmaxf(fabsf(dot), 1.0f + 1e-6f);
        float ex = __builtin_amdgcn_rcpf(xv + sqrtf(fmaf(xv, xv, -1.0f)));
        ex = on ? ex : 0.0f;
        den += ex;
#pragma unroll
        for (int d = 0; d < 16; ++d) acc[d] = fmaf(ex, vd[d], acc[d]);
    }

    // total softmax denominator for this head (all 16 lanes get it)
    float den_t = r16(den);

    // butterfly transpose-reduce: lane es ends with total for dim es.
    // round mask=8
    {
        float t8[8], n8[8];
#pragma unroll
        for (int j = 0; j < 8; ++j) t8[j] = (es & 8) ? acc[j] : acc[j + 8];
#pragma unroll
        for (int j = 0; j < 8; ++j) n8[j] = ((es & 8) ? acc[j + 8] : acc[j]) + __shfl_xor(t8[j], 8, 16);
        // round mask=4
        float t4[4], n4[4];
#pragma unroll
        for (int j = 0; j < 4; ++j) t4[j] = (es & 4) ? n8[j] : n8[j + 4];
#pragma unroll
        for (int j = 0; j < 4; ++j) n4[j] = ((es & 4) ? n8[j + 4] : n8[j]) + __shfl_xor(t4[j], 4, 16);
        // round mask=2
        float t2[2], n2[2];
#pragma unroll
        for (int j = 0; j < 2; ++j) t2[j] = (es & 2) ? n4[j] : n4[j + 2];
#pragma unroll
        for (int j = 0; j < 2; ++j) n2[j] = ((es & 2) ? n4[j + 2] : n4[j]) + __shfl_xor(t2[j], 2, 16);
        // round mask=1
        float t1 = (es & 1) ? n2[0] : n2[1];
        acc[0] = ((es & 1) ? n2[1] : n2[0]) + __shfl_xor(t1, 1, 16);
    }
    float a0 = acc[0];

    float ss = r16(a0 * a0);
    float att = 0.0f;
    if (ss > 0.0f) att = a0 / (sqrtf(ss) + 1e-9f * den_t);
    atts[tid] = att;
    __syncthreads();

    const float4* av = (const float4*)(atts + (tid & 192));
    const float4* wr = (const float4*)(Wo + t * 64);
    float o = 0.0f;
#pragma unroll
    for (int j = 0; j < 16; ++j) {
        float4 w = wr[j], a = av[j];
        o += a.x * w.x + a.y * w.y + a.z * w.z + a.w * w.w;
    }
    out[n * 64 + t] = o + bo[t];
}

extern "C" void kernel_launch(void* const* d_in, const int* in_sizes, int n_in,
                              void* d_out, int out_size, void* d_ws, size_t ws_size,
                              hipStream_t stream) {
    const float* x  = (const float*)d_in[0];
    const void*  ei = d_in[1];
    const float* Wq = (const float*)d_in[2];
    const float* bq = (const float*)d_in[3];
    const float* Wk = (const float*)d_in[4];
    const float* bk = (const float*)d_in[5];
    const float* Wv = (const float*)d_in[6];
    const float* bv = (const float*)d_in[7];
    const float* Wo = (const float*)d_in[8];
    const float* bo = (const float*)d_in[9];
    float* out = (float*)d_out;

    __half2* qv2  = (__half2*)d_ws;                           // N*64 half2 {qn|v}
    float* ktn    = (float*)(qv2 + (size_t)NNODES * 64);      // N*64 fp32
    int*   deg    = (int*)(ktn + (size_t)NNODES * 64);        // N
    int*   flg    = deg + NNODES;                             // 1
    int*   ssrc   = flg + 1;                                  // N*CAP

    // zero deg + flag (contiguous)
    hipMemsetAsync(deg, 0, (size_t)(NNODES + 1) * sizeof(int), stream);

    detect_kernel<<<1, 256, 0, stream>>>(ei, flg);
    qkv_kernel<<<(NNODES + 63) / 64, 256, 0, stream>>>(x, Wq, bq, Wk, bk, Wv, bv, qv2, ktn);
    build_kernel<<<(NEDGES + 255) / 256, 256, 0, stream>>>(ei, flg, deg, ssrc);
    agg_kernel<<<NNODES / 4, 256, 0, stream>>>(deg, ssrc, qv2, ktn, Wo, bo, out);
}